// Round 1
// baseline (786.064 us; speedup 1.0000x reference)
//
#include <hip/hip_runtime.h>
#include <math.h>

#define NTOK 3136           // 16*14*14 tokens
#define BATCH 4
#define MT (BATCH * NTOK)   // 12544
#define EDIM 256
#define KCONV 2304          // 3*3*16*16
#define THRESH 1.5f
#define LN_EPS 1e-5f

// ---------- wave helpers (wave = 64) ----------
__device__ __forceinline__ float wsum(float v) {
#pragma unroll
    for (int o = 32; o > 0; o >>= 1) v += __shfl_xor(v, o);
    return v;
}
__device__ __forceinline__ float wmax(float v) {
#pragma unroll
    for (int o = 32; o > 0; o >>= 1) v = fmaxf(v, __shfl_xor(v, o));
    return v;
}

// ---------- conv as implicit GEMM: out[m,e] = relu(sum_k A[m,k]*cw[e,k] + cb[e]) ----------
// m = b*3136 + d*196 + h*14 + w ; k = c*768 + kd*256 + kh*16 + kw
// A[m,k] = video[b, c, 2d-1+kd, 16h+kh, 16w+kw]  (zero when 2d-1+kd < 0)
__global__ __launch_bounds__(256) void conv_gemm_k(
    const float* __restrict__ video, const float* __restrict__ cw,
    const float* __restrict__ cb, float* __restrict__ out)
{
    __shared__ float As[32][68];   // [kk][row], 68-pad: 16B-aligned float4 rows, banks spread
    __shared__ float Bs[32][68];
    const int t  = threadIdx.x;
    const int m0 = blockIdx.x * 64;
    const int e0 = blockIdx.y * 64;
    const int kk = t & 31;
    const int rb = t >> 5;         // 0..7
    int vbase[8], dd[8];
#pragma unroll
    for (int i = 0; i < 8; i++) {
        int m = m0 + rb + i * 8;
        int b = m / NTOK, n = m % NTOK;
        int d = n / 196, hw = n % 196;
        int h = hw / 14, w = hw % 14;
        vbase[i] = (b * 96) * 50176 + (h * 16) * 224 + w * 16;
        dd[i] = d;
    }
    const int ty = t >> 4, tx = t & 15;
    float acc[4][4] = {};
    for (int k0 = 0; k0 < KCONV; k0 += 32) {
        int k  = k0 + kk;
        int c  = k / 768;
        int r  = k - c * 768;
        int kd = r >> 8;
        int r2 = r & 255;
        int koff = c * (32 * 50176) + (r2 >> 4) * 224 + (r2 & 15);
#pragma unroll
        for (int i = 0; i < 8; i++) {
            int id = 2 * dd[i] - 1 + kd;
            float a = 0.f;
            if (id >= 0) a = video[vbase[i] + id * 50176 + koff];
            As[kk][rb + i * 8] = a;
        }
#pragma unroll
        for (int i = 0; i < 8; i++)
            Bs[kk][rb + i * 8] = cw[(e0 + rb + i * 8) * KCONV + k];
        __syncthreads();
#pragma unroll
        for (int q = 0; q < 32; q++) {
            float4 a4 = *reinterpret_cast<const float4*>(&As[q][ty * 4]);
            float4 b4 = *reinterpret_cast<const float4*>(&Bs[q][tx * 4]);
            float a[4] = {a4.x, a4.y, a4.z, a4.w};
            float b[4] = {b4.x, b4.y, b4.z, b4.w};
#pragma unroll
            for (int i = 0; i < 4; i++)
#pragma unroll
                for (int j = 0; j < 4; j++) acc[i][j] += a[i] * b[j];
        }
        __syncthreads();
    }
#pragma unroll
    for (int i = 0; i < 4; i++) {
        int m = m0 + ty * 4 + i;
#pragma unroll
        for (int j = 0; j < 4; j++) {
            int e = e0 + tx * 4 + j;
            out[m * EDIM + e] = fmaxf(acc[i][j] + cb[e], 0.f);
        }
    }
}

// ---------- generic C[m,e] = sum_k A[m,k]*W[e,k] + bias[e] (+addvec[e]) (mask s>=S -> 0) ----------
__global__ __launch_bounds__(256) void gemm256_k(
    const float* __restrict__ A, const float* __restrict__ W,
    const float* __restrict__ bias, float* __restrict__ C,
    const float* __restrict__ addvec, const int* __restrict__ Sptr)
{
    __shared__ float As[32][68];
    __shared__ float Bs[32][68];
    const int t  = threadIdx.x;
    const int m0 = blockIdx.x * 64;
    const int e0 = blockIdx.y * 64;
    const int kk = t & 31;
    const int rb = t >> 5;
    const int ty = t >> 4, tx = t & 15;
    float acc[4][4] = {};
    for (int k0 = 0; k0 < 256; k0 += 32) {
#pragma unroll
        for (int i = 0; i < 8; i++)
            As[kk][rb + i * 8] = A[(m0 + rb + i * 8) * 256 + k0 + kk];
#pragma unroll
        for (int i = 0; i < 8; i++)
            Bs[kk][rb + i * 8] = W[(e0 + rb + i * 8) * 256 + k0 + kk];
        __syncthreads();
#pragma unroll
        for (int q = 0; q < 32; q++) {
            float4 a4 = *reinterpret_cast<const float4*>(&As[q][ty * 4]);
            float4 b4 = *reinterpret_cast<const float4*>(&Bs[q][tx * 4]);
            float a[4] = {a4.x, a4.y, a4.z, a4.w};
            float b[4] = {b4.x, b4.y, b4.z, b4.w};
#pragma unroll
            for (int i = 0; i < 4; i++)
#pragma unroll
                for (int j = 0; j < 4; j++) acc[i][j] += a[i] * b[j];
        }
        __syncthreads();
    }
    int S = Sptr ? *Sptr : 0;
#pragma unroll
    for (int i = 0; i < 4; i++) {
        int m = m0 + ty * 4 + i;
        int s = m % NTOK;
#pragma unroll
        for (int j = 0; j < 4; j++) {
            int e = e0 + tx * 4 + j;
            float v = acc[i][j] + bias[e];
            if (addvec) v += addvec[e];
            if (Sptr && s >= S) v = 0.f;
            C[m * 256 + e] = v;
        }
    }
}

// ---------- byte -> entropy -> boundary (b=0 only); one wave per token ----------
__global__ __launch_bounds__(256) void boundary_k(
    const float* __restrict__ tokens, const float* __restrict__ ent_table,
    int* __restrict__ boundary)
{
    int n    = blockIdx.x * 4 + (threadIdx.x >> 6);
    int lane = threadIdx.x & 63;
    const float4 x = reinterpret_cast<const float4*>(tokens + (size_t)n * 256)[lane];
    float mean = wsum(x.x + x.y + x.z + x.w) * (1.f / 256.f);
    float bf = rintf(mean * 255.f);           // round-half-even, matches jnp.round
    bf = fminf(fmaxf(bf, 0.f), 255.f);
    int byte = (int)bf;
    const float4 lg = reinterpret_cast<const float4*>(ent_table + byte * 256)[lane];
    float mx = wmax(fmaxf(fmaxf(lg.x, lg.y), fmaxf(lg.z, lg.w)));
    float e0 = expf(lg.x - mx), e1 = expf(lg.y - mx), e2 = expf(lg.z - mx), e3 = expf(lg.w - mx);
    float z = wsum(e0 + e1 + e2 + e3);
    float iz = 1.f / z;
    float p0 = e0 * iz, p1 = e1 * iz, p2 = e2 * iz, p3 = e3 * iz;
    float ep = -(p0 * log2f(p0 + 1e-9f) + p1 * log2f(p1 + 1e-9f) +
                 p2 * log2f(p2 + 1e-9f) + p3 * log2f(p3 + 1e-9f));
    ep = wsum(ep);
    if (lane == 0) boundary[n] = (ep > THRESH) ? 1 : 0;
}

// ---------- single-block scan: boundary -> seg_start[], S ----------
__global__ __launch_bounds__(256) void scan_k(const int* __restrict__ boundary,
    int* __restrict__ seg_start, int* __restrict__ Sptr)
{
    __shared__ int sums[256];
    const int t = threadIdx.x;
    const int CH = 13;                 // 256*13 >= 3136
    int base = t * CH;
    int s = 0;
    for (int i = 0; i < CH; i++) { int n = base + i; if (n < NTOK) s += boundary[n]; }
    sums[t] = s; __syncthreads();
    for (int o = 1; o < 256; o <<= 1) {
        int v = sums[t];
        int u = (t >= o) ? sums[t - o] : 0;
        __syncthreads();
        sums[t] = v + u;
        __syncthreads();
    }
    int run = (t == 0) ? 0 : sums[t - 1];   // seg id of token `base`
    if (t == 0) seg_start[0] = 0;
    for (int i = 0; i < CH; i++) {
        int n = base + i;
        if (n >= NTOK) break;
        int v = boundary[n];
        if (n == NTOK - 1) { Sptr[0] = run + 1; seg_start[run + 1] = NTOK; }
        if (v && (n + 1 < NTOK)) seg_start[run + 1] = n + 1;
        run += v;
    }
}

// ---------- row LayerNorm in place; one wave per row ----------
__global__ __launch_bounds__(256) void ln_k(float* __restrict__ X,
    const float* __restrict__ g, const float* __restrict__ b)
{
    int row  = blockIdx.x * 4 + (threadIdx.x >> 6);
    int lane = threadIdx.x & 63;
    float4* rp = reinterpret_cast<float4*>(X + (size_t)row * 256);
    float4 x = rp[lane];
    float m = wsum(x.x + x.y + x.z + x.w) * (1.f / 256.f);
    float d0 = x.x - m, d1 = x.y - m, d2 = x.z - m, d3 = x.w - m;
    float var = wsum(d0 * d0 + d1 * d1 + d2 * d2 + d3 * d3) * (1.f / 256.f);
    float inv = 1.f / sqrtf(var + LN_EPS);
    float4 g4 = reinterpret_cast<const float4*>(g)[lane];
    float4 b4 = reinterpret_cast<const float4*>(b)[lane];
    float4 y;
    y.x = d0 * inv * g4.x + b4.x;
    y.y = d1 * inv * g4.y + b4.y;
    y.z = d2 * inv * g4.z + b4.z;
    y.w = d3 * inv * g4.w + b4.w;
    rp[lane] = y;
}

// ---------- query path: qp[256], batch-invariant, one block ----------
__global__ __launch_bounds__(256) void query_k(
    const float* __restrict__ gq, const float* __restrict__ wq_w, const float* __restrict__ wq_b,
    const float* __restrict__ lnq_g, const float* __restrict__ lnq_b,
    const float* __restrict__ inW, const float* __restrict__ inB, float* __restrict__ qp)
{
    __shared__ float sh[256];
    __shared__ float red[256];
    const int t = threadIdx.x;
    float acc = wq_b[t];
    for (int j = 0; j < 256; j++) acc += gq[j] * wq_w[t * 256 + j];
    red[t] = acc; __syncthreads();
    for (int o = 128; o > 0; o >>= 1) { if (t < o) red[t] += red[t + o]; __syncthreads(); }
    float m = red[0] * (1.f / 256.f);
    __syncthreads();
    float d = acc - m;
    red[t] = d * d; __syncthreads();
    for (int o = 128; o > 0; o >>= 1) { if (t < o) red[t] += red[t + o]; __syncthreads(); }
    float inv = 1.f / sqrtf(red[0] * (1.f / 256.f) + LN_EPS);
    sh[t] = d * inv * lnq_g[t] + lnq_b[t];
    __syncthreads();
    float a2 = inB[t];                       // bqi
    for (int j = 0; j < 256; j++) a2 += sh[j] * inW[t * 256 + j];   // Wqi
    qp[t] = a2 * 0.125f;                     // dh^-0.5 = 64^-0.5
}

// ---------- scores[n,b,h] = dot(qp[h], kp[b,n,h]); one wave per (b,n) ----------
__global__ __launch_bounds__(256) void scores_k(const float* __restrict__ kp,
    const float* __restrict__ qp, float* __restrict__ sc)
{
    int idx  = blockIdx.x * 4 + (threadIdx.x >> 6);   // b*NTOK + n
    int lane = threadIdx.x & 63;
    float4 k4 = reinterpret_cast<const float4*>(kp + (size_t)idx * 256)[lane];
    float4 q4 = reinterpret_cast<const float4*>(qp)[lane];
    float p = k4.x * q4.x + k4.y * q4.y + k4.z * q4.z + k4.w * q4.w;
    p += __shfl_xor(p, 1); p += __shfl_xor(p, 2);
    p += __shfl_xor(p, 4); p += __shfl_xor(p, 8);     // reduce within 16-lane head group
    if ((lane & 15) == 0) {
        int b = idx / NTOK, n = idx % NTOK;
        int h = lane >> 4;
        sc[(b * 4 + h) * NTOK + n] = p;
    }
}

// ---------- segment softmax-attention; one wave per (segment, b) ----------
__global__ __launch_bounds__(256) void attn_k(const float* __restrict__ sc,
    const float* __restrict__ vp, const int* __restrict__ seg_start,
    const int* __restrict__ Sptr, float* __restrict__ attn)
{
    int s    = blockIdx.x;
    int b    = threadIdx.x >> 6;
    int lane = threadIdx.x & 63;
    float* orow = attn + ((size_t)b * NTOK + s) * 256;
    int S = *Sptr;
    if (s >= S) {
#pragma unroll
        for (int h = 0; h < 4; h++) orow[h * 64 + lane] = 0.f;
        return;
    }
    int st = seg_start[s], en = seg_start[s + 1];
    for (int h = 0; h < 4; h++) {
        const float* scr = sc + (b * 4 + h) * NTOK;
        float m = -1e30f;
        for (int n = st; n < en; n++) m = fmaxf(m, scr[n]);
        float den = 0.f, acc = 0.f;
        for (int n = st; n < en; n++) {
            float w = expf(scr[n] - m);
            den += w;
            acc += w * vp[((size_t)b * NTOK + n) * 256 + h * 64 + lane];
        }
        orow[h * 64 + lane] = acc / den;
    }
}

extern "C" void kernel_launch(void* const* d_in, const int* in_sizes, int n_in,
                              void* d_out, int out_size, void* d_ws, size_t ws_size,
                              hipStream_t stream)
{
    const float* video      = (const float*)d_in[0];
    const float* conv_w     = (const float*)d_in[1];
    const float* conv_b     = (const float*)d_in[2];
    const float* wq_w       = (const float*)d_in[3];
    const float* wq_b       = (const float*)d_in[4];
    const float* wk_w       = (const float*)d_in[5];
    const float* wk_b       = (const float*)d_in[6];
    const float* wv_w       = (const float*)d_in[7];
    const float* wv_b       = (const float*)d_in[8];
    const float* lnq_g      = (const float*)d_in[9];
    const float* lnq_b      = (const float*)d_in[10];
    const float* lnk_g      = (const float*)d_in[11];
    const float* lnk_b      = (const float*)d_in[12];
    const float* lnv_g      = (const float*)d_in[13];
    const float* lnv_b      = (const float*)d_in[14];
    const float* in_proj_w  = (const float*)d_in[15];
    const float* in_proj_b  = (const float*)d_in[16];
    const float* out_proj_w = (const float*)d_in[17];
    const float* out_proj_b = (const float*)d_in[18];
    const float* dense_w    = (const float*)d_in[19];
    const float* dense_b    = (const float*)d_in[20];
    const float* bproj_w    = (const float*)d_in[21];
    const float* bproj_b    = (const float*)d_in[22];
    const float* group_q    = (const float*)d_in[23];
    const float* ent_table  = (const float*)d_in[24];
    float* out = (float*)d_out;

    // workspace layout (~38.8 MB): three MT*256 fp32 buffers + glue
    float* W1 = (float*)d_ws;                       // tokens -> out1
    float* W2 = W1 + (size_t)MT * 256;              // preK/k, preV/v -> attn -> out2
    float* W3 = W2 + (size_t)MT * 256;              // kp -> vp
    float* sc = W3 + (size_t)MT * 256;              // scores (B*NH*NTOK)
    float* qp = sc + 16 * NTOK;
    int* boundary  = (int*)(qp + 256);
    int* seg_start = boundary + NTOK;
    int* Sp        = seg_start + (NTOK + 1);

    dim3 gG(196, 4), blk(256);
    conv_gemm_k<<<gG, blk, 0, stream>>>(video, conv_w, conv_b, W1);
    boundary_k<<<dim3(NTOK / 4), blk, 0, stream>>>(W1, ent_table, boundary);
    scan_k<<<dim3(1), blk, 0, stream>>>(boundary, seg_start, Sp);
    query_k<<<dim3(1), blk, 0, stream>>>(group_q, wq_w, wq_b, lnq_g, lnq_b,
                                         in_proj_w, in_proj_b, qp);
    // K path
    gemm256_k<<<gG, blk, 0, stream>>>(W1, wk_w, wk_b, W2, nullptr, nullptr);
    ln_k<<<dim3(MT / 4), blk, 0, stream>>>(W2, lnk_g, lnk_b);
    gemm256_k<<<gG, blk, 0, stream>>>(W2, in_proj_w + 256 * 256, in_proj_b + 256, W3,
                                      nullptr, nullptr);
    scores_k<<<dim3(MT / 4), blk, 0, stream>>>(W3, qp, sc);
    // V path
    gemm256_k<<<gG, blk, 0, stream>>>(W1, wv_w, wv_b, W2, nullptr, nullptr);
    ln_k<<<dim3(MT / 4), blk, 0, stream>>>(W2, lnv_g, lnv_b);
    gemm256_k<<<gG, blk, 0, stream>>>(W2, in_proj_w + 2 * 256 * 256, in_proj_b + 512, W3,
                                      nullptr, nullptr);
    // segment attention -> W2
    attn_k<<<dim3(NTOK), blk, 0, stream>>>(sc, W3, seg_start, Sp, W2);
    // tail projections
    gemm256_k<<<gG, blk, 0, stream>>>(W2, out_proj_w, out_proj_b, W1, nullptr, nullptr);
    gemm256_k<<<gG, blk, 0, stream>>>(W1, dense_w, dense_b, W2, group_q, nullptr);
    gemm256_k<<<gG, blk, 0, stream>>>(W2, bproj_w, bproj_b, out, nullptr, Sp);
}

// Round 2
// 420.152 us; speedup vs baseline: 1.8709x; 1.8709x over previous
//
#include <hip/hip_runtime.h>
#include <math.h>

#define NTOK 3136           // 16*14*14 tokens
#define MT 12544            // 4 * NTOK
#define KCV 2304            // 3*3*16*16
#define THRESH 1.5f
#define LN_EPS 1e-5f

typedef short short8 __attribute__((ext_vector_type(8)));
typedef float f32x4 __attribute__((ext_vector_type(4)));

// ---------- bf16 helpers (RTNE) ----------
__device__ __forceinline__ unsigned short f2bf(float f) {
    unsigned int u = __float_as_uint(f);
    u += 0x7fffu + ((u >> 16) & 1u);
    return (unsigned short)(u >> 16);
}
__device__ __forceinline__ float bf2f(unsigned short h) {
    return __uint_as_float(((unsigned int)h) << 16);
}
__device__ __forceinline__ void async16(const void* g, void* l) {
    __builtin_amdgcn_global_load_lds((const __attribute__((address_space(1))) void*)g,
                                     (__attribute__((address_space(3))) void*)l, 16, 0, 0);
}

// ---------- wave helpers (wave = 64) ----------
__device__ __forceinline__ float wsum(float v) {
#pragma unroll
    for (int o = 32; o > 0; o >>= 1) v += __shfl_xor(v, o);
    return v;
}
__device__ __forceinline__ float wmax(float v) {
#pragma unroll
    for (int o = 32; o > 0; o >>= 1) v = fmaxf(v, __shfl_xor(v, o));
    return v;
}

// ---------- weight prep: conv_w fp32 -> hi/lo bf16 ----------
__global__ __launch_bounds__(256) void split_cw_k(const float* __restrict__ cw,
    unsigned short* __restrict__ cwh, unsigned short* __restrict__ cwl)
{
    int i = blockIdx.x * 256 + threadIdx.x;
    if (i >= 256 * KCV) return;
    float a = cw[i];
    unsigned short h = f2bf(a);
    cwh[i] = h;
    cwl[i] = f2bf(a - bf2f(h));
}

// ---------- weight prep: 6 fp32 matrices -> one bf16 pool ----------
// offsets: wk 0, wv 65536, in_proj 131072 (3E*E), out_proj 327680, dense 393216, bproj 458752
__global__ __launch_bounds__(256) void cast_w_k(
    const float* __restrict__ s0, const float* __restrict__ s1, const float* __restrict__ s2,
    const float* __restrict__ s3, const float* __restrict__ s4, const float* __restrict__ s5,
    unsigned short* __restrict__ dst)
{
    int i = blockIdx.x * 256 + threadIdx.x;
    if (i >= 524288) return;
    float v;
    if      (i <  65536) v = s0[i];
    else if (i < 131072) v = s1[i - 65536];
    else if (i < 327680) v = s2[i - 131072];
    else if (i < 393216) v = s3[i - 327680];
    else if (i < 458752) v = s4[i - 393216];
    else                 v = s5[i - 458752];
    dst[i] = f2bf(v);
}

// ---------- conv as implicit GEMM on MFMA, fp32 accuracy via hi/lo bf16 split ----------
// out[m,e] = relu(sum_k A[m,k]*cw[e,k] + cb[e]);  A*B ~ Ah*Bh + Ah*Bl + Al*Bh
// LDS layout per tile: [kg(4)][row(64)][8 bf16] -> lane-contiguous 16B writes & frag reads
__global__ __launch_bounds__(256) void conv_mfma_k(
    const float* __restrict__ video, const unsigned short* __restrict__ cwh,
    const unsigned short* __restrict__ cwl, const float* __restrict__ cb,
    float* __restrict__ outF, unsigned short* __restrict__ outB)
{
    __shared__ __align__(16) unsigned short Ah[2048], Al[2048], Bh[2048], Bl[2048];
    const int t    = threadIdx.x;
    const int lane = t & 63;
    const int w    = t >> 6;         // wave id = kg chunk = 16-row strip
    const int m0   = blockIdx.x * 64;
    const int e0   = blockIdx.y * 64;
    const int l15  = lane & 15, lq = lane >> 4;

    // A row geometry: m = b*3136 + d*196 + h*14 + w'; k = c*768 + kd*256 + kh*16 + kw
    int m = m0 + lane;
    int b = m / NTOK, n = m % NTOK;
    int d = n / 196, hw = n % 196;
    int h = hw / 14, ww = hw % 14;
    const float* vb = video + (size_t)(b * 3) * (32 * 50176) + (h * 16) * 224 + ww * 16;
    int dbase = 2 * d - 1;

    f32x4 acc[4] = {};
    for (int step = 0; step < 72; ++step) {
        int k0  = step * 32 + w * 8;     // wave-uniform
        int c   = k0 / 768;
        int rem = k0 - c * 768;
        int kd  = rem >> 8;
        int r2  = rem & 255;             // kh*16 + kw, (r2&15) in {0,8}
        int id  = dbase + kd;
        float4 a0 = make_float4(0.f, 0.f, 0.f, 0.f), a1 = a0;
        if (id >= 0) {
            const float* p = vb + (size_t)c * (32 * 50176) + id * 50176 + (r2 >> 4) * 224 + (r2 & 15);
            a0 = *(const float4*)p;
            a1 = *(const float4*)(p + 4);
        }
        // B staging: async 16B/lane directly to LDS
        async16(cwh + (size_t)(e0 + lane) * KCV + k0, &Bh[w * 512]);
        async16(cwl + (size_t)(e0 + lane) * KCV + k0, &Bl[w * 512]);
        // A staging: split fp32 -> hi/lo bf16, one b128 write each
        float av[8] = {a0.x, a0.y, a0.z, a0.w, a1.x, a1.y, a1.z, a1.w};
        unsigned int ph[4], pl[4];
#pragma unroll
        for (int j = 0; j < 4; ++j) {
            unsigned short h0 = f2bf(av[2 * j]), h1 = f2bf(av[2 * j + 1]);
            unsigned short q0 = f2bf(av[2 * j] - bf2f(h0));
            unsigned short q1 = f2bf(av[2 * j + 1] - bf2f(h1));
            ph[j] = (unsigned int)h0 | ((unsigned int)h1 << 16);
            pl[j] = (unsigned int)q0 | ((unsigned int)q1 << 16);
        }
        *(uint4*)&Ah[w * 512 + lane * 8] = make_uint4(ph[0], ph[1], ph[2], ph[3]);
        *(uint4*)&Al[w * 512 + lane * 8] = make_uint4(pl[0], pl[1], pl[2], pl[3]);
        __syncthreads();
        // frags: A row = 16w + (l&15); k-chunk = l>>4
        short8 fah = *(const short8*)&Ah[(lq * 64 + w * 16 + l15) * 8];
        short8 fal = *(const short8*)&Al[(lq * 64 + w * 16 + l15) * 8];
#pragma unroll
        for (int ct = 0; ct < 4; ++ct) {
            short8 fbh = *(const short8*)&Bh[(lq * 64 + ct * 16 + l15) * 8];
            short8 fbl = *(const short8*)&Bl[(lq * 64 + ct * 16 + l15) * 8];
            acc[ct] = __builtin_amdgcn_mfma_f32_16x16x32_bf16(fah, fbh, acc[ct], 0, 0, 0);
            acc[ct] = __builtin_amdgcn_mfma_f32_16x16x32_bf16(fah, fbl, acc[ct], 0, 0, 0);
            acc[ct] = __builtin_amdgcn_mfma_f32_16x16x32_bf16(fal, fbh, acc[ct], 0, 0, 0);
        }
        __syncthreads();
    }
    // C/D: col = lane&15, row = (lane>>4)*4 + reg  [m89]
    int rbase = m0 + w * 16 + lq * 4;
#pragma unroll
    for (int ct = 0; ct < 4; ++ct) {
        int e = e0 + ct * 16 + l15;
        float bias = cb[e];
#pragma unroll
        for (int r = 0; r < 4; ++r) {
            float v = fmaxf(acc[ct][r] + bias, 0.f);
            size_t off = (size_t)(rbase + r) * 256 + e;
            outF[off] = v;
            outB[off] = f2bf(v);
        }
    }
}

// ---------- bf16 MFMA GEMM, K=256 staged fully in LDS (one barrier) ----------
// C[m,e] = sum_k A[m,k]*W[e,k] + bias[e] (+addvec[e]) (mask m%NTOK >= *Sptr -> 0)
__global__ __launch_bounds__(256) void gemm_mfma_k(
    const unsigned short* __restrict__ A, const unsigned short* __restrict__ W,
    const float* __restrict__ bias, const float* __restrict__ addvec,
    const int* __restrict__ Sptr, float* __restrict__ outF, unsigned short* __restrict__ outB)
{
    __shared__ __align__(16) unsigned short As[16384], Bs[16384];   // 32 KB + 32 KB
    const int t = threadIdx.x, lane = t & 63, w = t >> 6;
    const int m0 = blockIdx.x * 64, e0 = blockIdx.y * 64;
    const int l15 = lane & 15, lq = lane >> 4;
    const unsigned short* ga = A + (size_t)(m0 + lane) * 256;
    const unsigned short* gb = W + (size_t)(e0 + lane) * 256;
#pragma unroll
    for (int kg = w; kg < 32; kg += 4) {
        async16(ga + kg * 8, &As[kg * 512]);
        async16(gb + kg * 8, &Bs[kg * 512]);
    }
    f32x4 acc[4] = {};
    __syncthreads();
#pragma unroll
    for (int s = 0; s < 8; ++s) {
        int kg = s * 4 + lq;
        short8 a = *(const short8*)&As[(kg * 64 + w * 16 + l15) * 8];
#pragma unroll
        for (int ct = 0; ct < 4; ++ct) {
            short8 bb = *(const short8*)&Bs[(kg * 64 + ct * 16 + l15) * 8];
            acc[ct] = __builtin_amdgcn_mfma_f32_16x16x32_bf16(a, bb, acc[ct], 0, 0, 0);
        }
    }
    int S = Sptr ? *Sptr : 0x7fffffff;
    int rbase = m0 + w * 16 + lq * 4;
#pragma unroll
    for (int ct = 0; ct < 4; ++ct) {
        int e = e0 + ct * 16 + l15;
        float bv = bias[e] + (addvec ? addvec[e] : 0.f);
#pragma unroll
        for (int r = 0; r < 4; ++r) {
            int mm = rbase + r;
            float v = acc[ct][r] + bv;
            if ((mm % NTOK) >= S) v = 0.f;
            size_t off = (size_t)mm * 256 + e;
            if (outF) outF[off] = v;
            if (outB) outB[off] = f2bf(v);
        }
    }
}

// ---------- byte -> entropy -> boundary (b=0 only); one wave per token ----------
__global__ __launch_bounds__(256) void boundary_k(
    const float* __restrict__ tokens, const float* __restrict__ ent_table,
    int* __restrict__ boundary)
{
    int n    = blockIdx.x * 4 + (threadIdx.x >> 6);
    int lane = threadIdx.x & 63;
    const float4 x = reinterpret_cast<const float4*>(tokens + (size_t)n * 256)[lane];
    float mean = wsum(x.x + x.y + x.z + x.w) * (1.f / 256.f);
    float bf = rintf(mean * 255.f);
    bf = fminf(fmaxf(bf, 0.f), 255.f);
    int byte = (int)bf;
    const float4 lg = reinterpret_cast<const float4*>(ent_table + byte * 256)[lane];
    float mx = wmax(fmaxf(fmaxf(lg.x, lg.y), fmaxf(lg.z, lg.w)));
    float e0 = expf(lg.x - mx), e1 = expf(lg.y - mx), e2 = expf(lg.z - mx), e3 = expf(lg.w - mx);
    float z = wsum(e0 + e1 + e2 + e3);
    float iz = 1.f / z;
    float p0 = e0 * iz, p1 = e1 * iz, p2 = e2 * iz, p3 = e3 * iz;
    float ep = -(p0 * log2f(p0 + 1e-9f) + p1 * log2f(p1 + 1e-9f) +
                 p2 * log2f(p2 + 1e-9f) + p3 * log2f(p3 + 1e-9f));
    ep = wsum(ep);
    if (lane == 0) boundary[n] = (ep > THRESH) ? 1 : 0;
}

// ---------- single-block scan: boundary -> seg_start[], S ----------
__global__ __launch_bounds__(256) void scan_k(const int* __restrict__ boundary,
    int* __restrict__ seg_start, int* __restrict__ Sptr)
{
    __shared__ int sums[256];
    const int t = threadIdx.x;
    const int CH = 13;
    int base = t * CH;
    int s = 0;
    for (int i = 0; i < CH; i++) { int n = base + i; if (n < NTOK) s += boundary[n]; }
    sums[t] = s; __syncthreads();
    for (int o = 1; o < 256; o <<= 1) {
        int v = sums[t];
        int u = (t >= o) ? sums[t - o] : 0;
        __syncthreads();
        sums[t] = v + u;
        __syncthreads();
    }
    int run = (t == 0) ? 0 : sums[t - 1];
    if (t == 0) seg_start[0] = 0;
    for (int i = 0; i < CH; i++) {
        int n = base + i;
        if (n >= NTOK) break;
        int v = boundary[n];
        if (n == NTOK - 1) { Sptr[0] = run + 1; seg_start[run + 1] = NTOK; }
        if (v && (n + 1 < NTOK)) seg_start[run + 1] = n + 1;
        run += v;
    }
}

// ---------- row LayerNorm: fp32 in -> bf16 out; one wave per row ----------
__global__ __launch_bounds__(256) void ln_bf_k(const float* __restrict__ X,
    const float* __restrict__ g, const float* __restrict__ b, unsigned short* __restrict__ Y)
{
    int row  = blockIdx.x * 4 + (threadIdx.x >> 6);
    int lane = threadIdx.x & 63;
    float4 x = reinterpret_cast<const float4*>(X + (size_t)row * 256)[lane];
    float m = wsum(x.x + x.y + x.z + x.w) * (1.f / 256.f);
    float d0 = x.x - m, d1 = x.y - m, d2 = x.z - m, d3 = x.w - m;
    float var = wsum(d0 * d0 + d1 * d1 + d2 * d2 + d3 * d3) * (1.f / 256.f);
    float inv = 1.f / sqrtf(var + LN_EPS);
    float4 g4 = reinterpret_cast<const float4*>(g)[lane];
    float4 b4 = reinterpret_cast<const float4*>(b)[lane];
    ushort4 y;
    y.x = f2bf(d0 * inv * g4.x + b4.x);
    y.y = f2bf(d1 * inv * g4.y + b4.y);
    y.z = f2bf(d2 * inv * g4.z + b4.z);
    y.w = f2bf(d3 * inv * g4.w + b4.w);
    reinterpret_cast<ushort4*>(Y + (size_t)row * 256)[lane] = y;
}

// ---------- query path: qp[256], batch-invariant, one block, fp32 ----------
__global__ __launch_bounds__(256) void query_k(
    const float* __restrict__ gq, const float* __restrict__ wq_w, const float* __restrict__ wq_b,
    const float* __restrict__ lnq_g, const float* __restrict__ lnq_b,
    const float* __restrict__ inW, const float* __restrict__ inB, float* __restrict__ qp)
{
    __shared__ float sh[256];
    __shared__ float red[256];
    const int t = threadIdx.x;
    float acc = wq_b[t];
    for (int j = 0; j < 256; j++) acc += gq[j] * wq_w[t * 256 + j];
    red[t] = acc; __syncthreads();
    for (int o = 128; o > 0; o >>= 1) { if (t < o) red[t] += red[t + o]; __syncthreads(); }
    float m = red[0] * (1.f / 256.f);
    __syncthreads();
    float d = acc - m;
    red[t] = d * d; __syncthreads();
    for (int o = 128; o > 0; o >>= 1) { if (t < o) red[t] += red[t + o]; __syncthreads(); }
    float inv = 1.f / sqrtf(red[0] * (1.f / 256.f) + LN_EPS);
    sh[t] = d * inv * lnq_g[t] + lnq_b[t];
    __syncthreads();
    float a2 = inB[t];
    for (int j = 0; j < 256; j++) a2 += sh[j] * inW[t * 256 + j];
    qp[t] = a2 * 0.125f;
}

// ---------- scores[n,b,h] = dot(qp[h], kp[b,n,h]); kp bf16; one wave per (b,n) ----------
__global__ __launch_bounds__(256) void scores_k(const unsigned short* __restrict__ kp,
    const float* __restrict__ qp, float* __restrict__ sc)
{
    int idx  = blockIdx.x * 4 + (threadIdx.x >> 6);   // b*NTOK + n
    int lane = threadIdx.x & 63;
    ushort4 k4 = reinterpret_cast<const ushort4*>(kp + (size_t)idx * 256)[lane];
    float4 q4 = reinterpret_cast<const float4*>(qp)[lane];
    float p = bf2f(k4.x) * q4.x + bf2f(k4.y) * q4.y + bf2f(k4.z) * q4.z + bf2f(k4.w) * q4.w;
    p += __shfl_xor(p, 1); p += __shfl_xor(p, 2);
    p += __shfl_xor(p, 4); p += __shfl_xor(p, 8);
    if ((lane & 15) == 0) {
        int b = idx / NTOK, n = idx % NTOK;
        int h = lane >> 4;
        sc[(b * 4 + h) * NTOK + n] = p;
    }
}

// ---------- segment softmax-attention; vp bf16 in, attn bf16 out ----------
__global__ __launch_bounds__(256) void attn_bf_k(const float* __restrict__ sc,
    const unsigned short* __restrict__ vp, const int* __restrict__ seg_start,
    const int* __restrict__ Sptr, unsigned short* __restrict__ attn)
{
    int s    = blockIdx.x;
    int b    = threadIdx.x >> 6;
    int lane = threadIdx.x & 63;
    unsigned short* orow = attn + ((size_t)b * NTOK + s) * 256;
    int S = *Sptr;
    if (s >= S) {
#pragma unroll
        for (int h = 0; h < 4; h++) orow[h * 64 + lane] = 0;
        return;
    }
    int st = seg_start[s], en = seg_start[s + 1];
    for (int h = 0; h < 4; h++) {
        const float* scr = sc + (b * 4 + h) * NTOK;
        float m = -1e30f;
        for (int n = st; n < en; n++) m = fmaxf(m, scr[n]);
        float den = 0.f, acc = 0.f;
        for (int n = st; n < en; n++) {
            float wgt = expf(scr[n] - m);
            den += wgt;
            acc += wgt * bf2f(vp[((size_t)b * NTOK + n) * 256 + h * 64 + lane]);
        }
        orow[h * 64 + lane] = f2bf(acc / den);
    }
}

extern "C" void kernel_launch(void* const* d_in, const int* in_sizes, int n_in,
                              void* d_out, int out_size, void* d_ws, size_t ws_size,
                              hipStream_t stream)
{
    const float* video      = (const float*)d_in[0];
    const float* conv_w     = (const float*)d_in[1];
    const float* conv_b     = (const float*)d_in[2];
    const float* wq_w       = (const float*)d_in[3];
    const float* wq_b       = (const float*)d_in[4];
    const float* wk_w       = (const float*)d_in[5];
    const float* wk_b       = (const float*)d_in[6];
    const float* wv_w       = (const float*)d_in[7];
    const float* wv_b       = (const float*)d_in[8];
    const float* lnq_g      = (const float*)d_in[9];
    const float* lnq_b      = (const float*)d_in[10];
    const float* lnk_g      = (const float*)d_in[11];
    const float* lnk_b      = (const float*)d_in[12];
    const float* lnv_g      = (const float*)d_in[13];
    const float* lnv_b      = (const float*)d_in[14];
    const float* in_proj_w  = (const float*)d_in[15];
    const float* in_proj_b  = (const float*)d_in[16];
    const float* out_proj_w = (const float*)d_in[17];
    const float* out_proj_b = (const float*)d_in[18];
    const float* dense_w    = (const float*)d_in[19];
    const float* dense_b    = (const float*)d_in[20];
    const float* bproj_w    = (const float*)d_in[21];
    const float* bproj_b    = (const float*)d_in[22];
    const float* group_q    = (const float*)d_in[23];
    const float* ent_table  = (const float*)d_in[24];
    float* out = (float*)d_out;

    // ---- workspace layout (~49 MB) ----
    float* W1f = (float*)d_ws;                         // fp32 tokens (for byte path)
    float* P   = W1f + (size_t)MT * 256;               // fp32 pre-LN buffer
    unsigned short* B1 = (unsigned short*)(P + (size_t)MT * 256);  // tokens_b16 / attn_b16
    unsigned short* B2 = B1 + (size_t)MT * 256;        // kln/vln/o1
    unsigned short* B3 = B2 + (size_t)MT * 256;        // kp/vp/o2
    unsigned short* cwh = B3 + (size_t)MT * 256;       // conv weights hi
    unsigned short* cwl = cwh + 256 * KCV;             // conv weights lo
    unsigned short* wpool = cwl + 256 * KCV;           // 524288 bf16 weights
    float* sc = (float*)(wpool + 524288);              // scores [B*NH][NTOK]
    float* qp = sc + 16 * NTOK;
    int* boundary  = (int*)(qp + 256);
    int* seg_start = boundary + NTOK;
    int* Sp        = seg_start + (NTOK + 1);

    const unsigned short* wkb    = wpool;
    const unsigned short* wvb    = wpool + 65536;
    const unsigned short* inpb   = wpool + 131072;     // 3E x E
    const unsigned short* outpb  = wpool + 327680;
    const unsigned short* denseb = wpool + 393216;
    const unsigned short* bprojb = wpool + 458752;

    dim3 gG(196, 4), blk(256);
    split_cw_k<<<dim3((256 * KCV) / 256), blk, 0, stream>>>(conv_w, cwh, cwl);
    cast_w_k<<<dim3(2048), blk, 0, stream>>>(wk_w, wv_w, in_proj_w, out_proj_w,
                                             dense_w, bproj_w, wpool);
    conv_mfma_k<<<gG, blk, 0, stream>>>(video, cwh, cwl, conv_b, W1f, B1);
    boundary_k<<<dim3(NTOK / 4), blk, 0, stream>>>(W1f, ent_table, boundary);
    scan_k<<<dim3(1), blk, 0, stream>>>(boundary, seg_start, Sp);
    query_k<<<dim3(1), blk, 0, stream>>>(group_q, wq_w, wq_b, lnq_g, lnq_b,
                                         in_proj_w, in_proj_b, qp);
    // K path
    gemm_mfma_k<<<gG, blk, 0, stream>>>(B1, wkb, wk_b, nullptr, nullptr, P, nullptr);
    ln_bf_k<<<dim3(MT / 4), blk, 0, stream>>>(P, lnk_g, lnk_b, B2);
    gemm_mfma_k<<<gG, blk, 0, stream>>>(B2, inpb + 65536, in_proj_b + 256,
                                        nullptr, nullptr, nullptr, B3);   // kp
    scores_k<<<dim3(MT / 4), blk, 0, stream>>>(B3, qp, sc);
    // V path
    gemm_mfma_k<<<gG, blk, 0, stream>>>(B1, wvb, wv_b, nullptr, nullptr, P, nullptr);
    ln_bf_k<<<dim3(MT / 4), blk, 0, stream>>>(P, lnv_g, lnv_b, B2);
    gemm_mfma_k<<<gG, blk, 0, stream>>>(B2, inpb + 131072, in_proj_b + 512,
                                        nullptr, nullptr, nullptr, B3);   // vp
    // segment attention
    attn_bf_k<<<dim3(NTOK), blk, 0, stream>>>(sc, B3, seg_start, Sp, B1);
    // tail projections
    gemm_mfma_k<<<gG, blk, 0, stream>>>(B1, outpb, out_proj_b, nullptr, nullptr, nullptr, B2);
    gemm_mfma_k<<<gG, blk, 0, stream>>>(B2, denseb, dense_b, group_q, nullptr, nullptr, B3);
    gemm_mfma_k<<<gG, blk, 0, stream>>>(B3, bprojb, bproj_b, nullptr, Sp, out, nullptr);
}